// Round 1
// baseline (1987.728 us; speedup 1.0000x reference)
//
#include <hip/hip_runtime.h>
#include <math.h>

#define BB 8
#define LL 2500
#define VV 50000
#define EE 100
#define FF 50
#define CC 8921
#define KK 10
#define PADW 5
#define LOUT 2501  // L + 2*PAD - K + 1

// ---------------------------------------------------------------------------
// K1: embedding + conv1d + bias + tanh  ->  Z (B, LOUT, F) fp32
// grid (ceil(LOUT/64), B), block 256 (4 waves; wave w handles f = w + 4*j)
// ---------------------------------------------------------------------------
__global__ void k1_conv(const int* __restrict__ text,
                        const float* __restrict__ embed,
                        const float* __restrict__ convw,
                        const float* __restrict__ convb,
                        float* __restrict__ Z) {
  __shared__ float xw[73 * 101];  // 73 rows x 100 (pad to 101: conflict-free)
  const int b   = blockIdx.y;
  const int l0  = blockIdx.x * 64;
  const int tid = threadIdx.x;

  // stage embedding window rows t = l0-5 .. l0+67 (zeros outside [0,L))
  for (int idx = tid; idx < 73 * 100; idx += 256) {
    int r = idx / 100;
    int e = idx - r * 100;
    int t = l0 - PADW + r;
    float v = 0.f;
    if (t >= 0 && t < LL) {
      int tok = text[b * LL + t];
      v = embed[tok * EE + e];
    }
    xw[r * 101 + e] = v;
  }
  __syncthreads();

  const int ll = tid & 63;                                  // local output row
  const int fg = __builtin_amdgcn_readfirstlane(tid >> 6);  // wave id 0..3
  const int l  = l0 + ll;

  float acc[13];
#pragma unroll
  for (int j = 0; j < 13; ++j) {
    int f = fg + 4 * j;
    acc[j] = (f < FF) ? convb[f] : 0.f;
  }

  for (int e = 0; e < EE; ++e) {
    float xk[KK];
#pragma unroll
    for (int k = 0; k < KK; ++k) xk[k] = xw[(ll + k) * 101 + e];
#pragma unroll
    for (int j = 0; j < 13; ++j) {
      int f = fg + 4 * j;
      if (f < FF) {
        const float* wp = convw + (f * EE + e) * KK;  // uniform -> s_load
#pragma unroll
        for (int k = 0; k < KK; ++k) acc[j] += xk[k] * wp[k];
      }
    }
  }

  if (l < LOUT) {
#pragma unroll
    for (int j = 0; j < 13; ++j) {
      int f = fg + 4 * j;
      if (f < FF) Z[((size_t)b * LOUT + l) * FF + f] = tanhf(acc[j]);
    }
  }
}

// ---------------------------------------------------------------------------
// K2: scores[b,c,l] = dot(Qw[c], Z[b,l]) -> written to alpha region (raw),
//     plus per-(b,c) online softmax max m and denom d.
// grid (ceil(C/16), B), block 256; lanes span l, 16 c per block.
// ---------------------------------------------------------------------------
__global__ void k2_scores(const float* __restrict__ Z,
                          const float* __restrict__ Qw,
                          float* __restrict__ scoresOut,
                          float* __restrict__ mOut,
                          float* __restrict__ dOut) {
  const int b   = blockIdx.y;
  const int c0  = blockIdx.x * 16;
  const int tid = threadIdx.x;
  const float* Zb = Z + (size_t)b * LOUT * FF;

  float m[16], d[16];
#pragma unroll
  for (int i = 0; i < 16; ++i) { m[i] = -1e30f; d[i] = 0.f; }

  for (int l = tid; l < LOUT; l += 256) {
    float zrow[FF];
    const float2* zp = (const float2*)(Zb + (size_t)l * FF);
#pragma unroll
    for (int i = 0; i < FF / 2; ++i) {
      float2 v = zp[i];
      zrow[2 * i] = v.x; zrow[2 * i + 1] = v.y;
    }
#pragma unroll
    for (int ci = 0; ci < 16; ++ci) {
      int c  = c0 + ci;
      int cc = (c < CC) ? c : (CC - 1);
      const float* qp = Qw + cc * FF;  // block-uniform -> s_load
      float s = 0.f;
#pragma unroll
      for (int f = 0; f < FF; ++f) s += qp[f] * zrow[f];
      if (c < CC) scoresOut[((size_t)(b * CC + c)) * LOUT + l] = s;
      float mo = m[ci];
      float mn = fmaxf(mo, s);
      d[ci] = d[ci] * __expf(mo - mn) + __expf(s - mn);
      m[ci] = mn;
    }
  }

  // reduce (m,d) across 256 threads per c
  __shared__ float red[16 * 4 * 2];
  const int lane = tid & 63, wid = tid >> 6;
#pragma unroll
  for (int ci = 0; ci < 16; ++ci) {
    float mm = m[ci], dd = d[ci];
    for (int off = 1; off < 64; off <<= 1) {
      float m2 = __shfl_xor(mm, off);
      float d2 = __shfl_xor(dd, off);
      float mn = fmaxf(mm, m2);
      dd = dd * __expf(mm - mn) + d2 * __expf(m2 - mn);
      mm = mn;
    }
    if (lane == 0) { red[ci * 4 + wid] = mm; red[64 + ci * 4 + wid] = dd; }
  }
  __syncthreads();
  if (tid < 16) {
    float mm = red[tid * 4], dd = red[64 + tid * 4];
#pragma unroll
    for (int w = 1; w < 4; ++w) {
      float m2 = red[tid * 4 + w], d2 = red[64 + tid * 4 + w];
      float mn = fmaxf(mm, m2);
      dd = dd * __expf(mm - mn) + d2 * __expf(m2 - mn);
      mm = mn;
    }
    int c = c0 + tid;
    if (c < CC) { mOut[b * CC + c] = mm; dOut[b * CC + c] = dd; }
  }
}

// ---------------------------------------------------------------------------
// K3: alpha = exp(s - m)/d (in-place over scores), and
//     logits[b,c] = sum_l alpha * dot(out_w[c], Z[b,l]) + out_b[c]
// grid (ceil(C/16), B), block 256
// ---------------------------------------------------------------------------
__global__ void k3_alpha(const float* __restrict__ Z,
                         const float* __restrict__ outw,
                         const float* __restrict__ outb,
                         const float* __restrict__ mIn,
                         const float* __restrict__ dIn,
                         float* __restrict__ alpha,
                         float* __restrict__ logits) {
  const int b   = blockIdx.y;
  const int c0  = blockIdx.x * 16;
  const int tid = threadIdx.x;
  const float* Zb = Z + (size_t)b * LOUT * FF;

  float mv[16], rd[16], lacc[16];
#pragma unroll
  for (int ci = 0; ci < 16; ++ci) {
    int c  = c0 + ci;
    int cc = (c < CC) ? c : (CC - 1);
    mv[ci]  = mIn[b * CC + cc];
    rd[ci]  = 1.f / dIn[b * CC + cc];
    lacc[ci] = 0.f;
  }

  for (int l = tid; l < LOUT; l += 256) {
    float zrow[FF];
    const float2* zp = (const float2*)(Zb + (size_t)l * FF);
#pragma unroll
    for (int i = 0; i < FF / 2; ++i) {
      float2 v = zp[i];
      zrow[2 * i] = v.x; zrow[2 * i + 1] = v.y;
    }
#pragma unroll
    for (int ci = 0; ci < 16; ++ci) {
      int c = c0 + ci;
      if (c < CC) {
        size_t idx = ((size_t)(b * CC + c)) * LOUT + l;
        float s = alpha[idx];
        float a = __expf(s - mv[ci]) * rd[ci];
        alpha[idx] = a;
        const float* op = outw + c * FF;  // block-uniform -> s_load
        float t = 0.f;
#pragma unroll
        for (int f = 0; f < FF; ++f) t += op[f] * zrow[f];
        lacc[ci] += a * t;
      }
    }
  }

  __shared__ float red[16 * 4];
  const int lane = tid & 63, wid = tid >> 6;
#pragma unroll
  for (int ci = 0; ci < 16; ++ci) {
    float v = lacc[ci];
    for (int off = 1; off < 64; off <<= 1) v += __shfl_xor(v, off);
    if (lane == 0) red[ci * 4 + wid] = v;
  }
  __syncthreads();
  if (tid < 16) {
    int c = c0 + tid;
    if (c < CC) {
      float v = red[tid * 4] + red[tid * 4 + 1] + red[tid * 4 + 2] + red[tid * 4 + 3];
      logits[b * CC + c] = v + outb[c];
    }
  }
}

// ---------------------------------------------------------------------------
extern "C" void kernel_launch(void* const* d_in, const int* in_sizes, int n_in,
                              void* d_out, int out_size, void* d_ws, size_t ws_size,
                              hipStream_t stream) {
  const int*   text  = (const int*)d_in[0];
  const float* embed = (const float*)d_in[1];
  const float* convw = (const float*)d_in[2];
  const float* convb = (const float*)d_in[3];
  const float* Qw    = (const float*)d_in[4];
  const float* outw  = (const float*)d_in[5];
  const float* outb  = (const float*)d_in[6];

  float* out    = (float*)d_out;
  float* logits = out;
  float* alpha  = out + (size_t)BB * CC;  // (B, C, LOUT)

  float* ws   = (float*)d_ws;
  float* Zbuf = ws;                               // B*LOUT*F floats (~4 MB)
  float* mBuf = ws + (size_t)BB * LOUT * FF;      // B*C floats
  float* dBuf = mBuf + (size_t)BB * CC;           // B*C floats

  k1_conv<<<dim3((LOUT + 63) / 64, BB), 256, 0, stream>>>(
      text, embed, convw, convb, Zbuf);
  k2_scores<<<dim3((CC + 15) / 16, BB), 256, 0, stream>>>(
      Zbuf, Qw, alpha, mBuf, dBuf);
  k3_alpha<<<dim3((CC + 15) / 16, BB), 256, 0, stream>>>(
      Zbuf, outw, outb, mBuf, dBuf, alpha, logits);
}

// Round 2
// 681.128 us; speedup vs baseline: 2.9183x; 2.9183x over previous
//
#include <hip/hip_runtime.h>
#include <math.h>

#define BB 8
#define LL 2500
#define VV 50000
#define EE 100
#define FF 50
#define CC 8921
#define KK 10
#define PADW 5
#define LOUT 2501        // L + 2*PAD - K + 1
#define NLT 157          // ceil(LOUT/16)
#define LPAD (NLT * 16)  // 2512
#define NCT 140          // ceil(CC/64)
#define NT16 (NCT * 4)   // 560 16-c tiles

typedef __attribute__((ext_vector_type(8))) short bf16x8;
typedef __attribute__((ext_vector_type(4))) float f32x4;

__device__ __forceinline__ short to_bf16(float f) {
  unsigned u = __builtin_bit_cast(unsigned, f);
  u += 0x7FFFu + ((u >> 16) & 1u);  // RNE
  return (short)(u >> 16);
}

// ---------------------------------------------------------------------------
// K1: embedding + conv1d + bias + tanh -> Z16 (B, LPAD, 64) bf16 row-major
// (k 50..63 zero, l 2501..2511 zero).  grid (40, B), block 256.
// ---------------------------------------------------------------------------
__global__ void k1_conv(const int* __restrict__ text,
                        const float* __restrict__ embed,
                        const float* __restrict__ convw,
                        const float* __restrict__ convb,
                        short* __restrict__ Z16) {
  __shared__ float xw[73 * 101];
  const int b   = blockIdx.y;
  const int l0  = blockIdx.x * 64;
  const int tid = threadIdx.x;

  for (int idx = tid; idx < 73 * 100; idx += 256) {
    int r = idx / 100;
    int e = idx - r * 100;
    int t = l0 - PADW + r;
    float v = 0.f;
    if (t >= 0 && t < LL) {
      int tok = text[b * LL + t];
      v = embed[tok * EE + e];
    }
    xw[r * 101 + e] = v;
  }
  __syncthreads();

  const int ll = tid & 63;
  const int fg = __builtin_amdgcn_readfirstlane(tid >> 6);
  const int l  = l0 + ll;

  float acc[13];
#pragma unroll
  for (int j = 0; j < 13; ++j) {
    int f = fg + 4 * j;
    acc[j] = (f < FF) ? convb[f] : 0.f;
  }

  for (int e = 0; e < EE; ++e) {
    float xk[KK];
#pragma unroll
    for (int k = 0; k < KK; ++k) xk[k] = xw[(ll + k) * 101 + e];
#pragma unroll
    for (int j = 0; j < 13; ++j) {
      int f = fg + 4 * j;
      if (f < FF) {
        const float* wp = convw + (f * EE + e) * KK;
#pragma unroll
        for (int k = 0; k < KK; ++k) acc[j] += xk[k] * wp[k];
      }
    }
  }

  if (l < LPAD) {
#pragma unroll
    for (int j = 0; j < 13; ++j) {
      int f = fg + 4 * j;
      if (f < FF) {
        float v = (l < LOUT) ? tanhf(acc[j]) : 0.f;
        Z16[((size_t)b * LPAD + l) * 64 + f] = to_bf16(v);
      }
    }
  }
  // zero-fill k = 50..63 for rows l0..l0+63 (clamped to LPAD)
  for (int idx = tid; idx < 64 * 14; idx += 256) {
    int r = idx / 14, k = 50 + idx % 14;
    int lz = l0 + r;
    if (lz < LPAD) Z16[((size_t)b * LPAD + lz) * 64 + k] = 0;
  }
}

// ---------------------------------------------------------------------------
// Pack Qw / out_w (C,F) fp32 -> frag layout bf16 [t16][kh][lane][8]
// frag elem j of lane: row c = t16*16 + (lane&15),
//                      k = 4*(lane>>4) + (j&3) + 16*(j>>2) + 32*kh
// ---------------------------------------------------------------------------
__global__ void k_packW(const float* __restrict__ W, short* __restrict__ Wp) {
  int u = blockIdx.x * 256 + threadIdx.x;  // < NT16*2*64
  int lane = u & 63, kh = (u >> 6) & 1, t16 = u >> 7;
  int c  = t16 * 16 + (lane & 15);
  int k0 = 4 * (lane >> 4) + 32 * kh;
  union { short s[8]; uint4 v; } o;
#pragma unroll
  for (int j = 0; j < 8; ++j) {
    int k = k0 + (j & 3) + 16 * (j >> 2);
    float val = (c < CC && k < FF) ? W[c * FF + k] : 0.f;
    o.s[j] = to_bf16(val);
  }
  ((uint4*)Wp)[u] = o.v;
}

// ---------------------------------------------------------------------------
// Pack Z16 row-major -> frag layout bf16 [b][lt][kh][lane][8]
// ---------------------------------------------------------------------------
__global__ void k_packZ(const short* __restrict__ Z16, short* __restrict__ Zp) {
  int u = blockIdx.x * 256 + threadIdx.x;  // < B*NLT*2*64
  int lane = u & 63, kh = (u >> 6) & 1, t = u >> 7;
  int lt = t % NLT, b = t / NLT;
  int l  = lt * 16 + (lane & 15);
  int k0 = 4 * (lane >> 4) + 32 * kh;
  const short* src = Z16 + ((size_t)b * LPAD + l) * 64 + k0;
  uint2 a  = *(const uint2*)src;          // j = 0..3  (k0..k0+3)
  uint2 bb = *(const uint2*)(src + 16);   // j = 4..7  (k0+16..k0+19)
  uint4 o; o.x = a.x; o.y = a.y; o.z = bb.x; o.w = bb.y;
  ((uint4*)Zp)[u] = o;
}

// ---------------------------------------------------------------------------
// Fused attention: per (b, 64-c tile).  Pass A: d = sum_l exp(s) via MFMA.
// Pass B: recompute s, alpha = exp(s)/d -> write; logits += alpha * t (MFMA).
// ---------------------------------------------------------------------------
__global__ __launch_bounds__(256) void k_attn(
    const short* __restrict__ Zp, const short* __restrict__ Qp,
    const short* __restrict__ Op, const float* __restrict__ outb,
    float* __restrict__ alpha, float* __restrict__ logits) {
  const int b    = blockIdx.y;
  const int ct   = blockIdx.x;
  const int tid  = threadIdx.x;
  const int w    = tid >> 6;
  const int lane = tid & 63;
  const int g    = lane >> 4, col = lane & 15;
  const int cb   = ct * 64;

  // hoisted A-fragments (Qw and out_w), 16 c rows per m-frag
  bf16x8 qf[4][2], of[4][2];
#pragma unroll
  for (int mf = 0; mf < 4; ++mf)
#pragma unroll
    for (int kh = 0; kh < 2; ++kh) {
      int t16 = ct * 4 + mf;
      qf[mf][kh] = ((const bf16x8*)Qp)[(t16 * 2 + kh) * 64 + lane];
      of[mf][kh] = ((const bf16x8*)Op)[(t16 * 2 + kh) * 64 + lane];
    }
  const bf16x8* Zb = (const bf16x8*)Zp + (size_t)b * NLT * 2 * 64;

  float dacc[4][4];
#pragma unroll
  for (int mf = 0; mf < 4; ++mf)
#pragma unroll
    for (int r = 0; r < 4; ++r) dacc[mf][r] = 0.f;

  // ---- pass A ----
  for (int lt = w; lt < NLT; lt += 4) {
    bf16x8 z0 = Zb[(lt * 2 + 0) * 64 + lane];
    bf16x8 z1 = Zb[(lt * 2 + 1) * 64 + lane];
    int   l    = lt * 16 + col;
    float lmsk = (l < LOUT) ? 1.f : 0.f;
#pragma unroll
    for (int mf = 0; mf < 4; ++mf) {
      f32x4 acc = {0.f, 0.f, 0.f, 0.f};
      acc = __builtin_amdgcn_mfma_f32_16x16x32_bf16(qf[mf][0], z0, acc, 0, 0, 0);
      acc = __builtin_amdgcn_mfma_f32_16x16x32_bf16(qf[mf][1], z1, acc, 0, 0, 0);
#pragma unroll
      for (int r = 0; r < 4; ++r) dacc[mf][r] += lmsk * __expf(acc[r]);
    }
  }

  // reduce d over 16 cols (butterfly), then over waves via LDS
  __shared__ float red[4][4][4][4];  // [w][mf][g][r]
  __shared__ float rdinv[64];
#pragma unroll
  for (int mf = 0; mf < 4; ++mf)
#pragma unroll
    for (int r = 0; r < 4; ++r) {
      float v = dacc[mf][r];
      v += __shfl_xor(v, 1); v += __shfl_xor(v, 2);
      v += __shfl_xor(v, 4); v += __shfl_xor(v, 8);
      dacc[mf][r] = v;
    }
  if (col == 0)
#pragma unroll
    for (int mf = 0; mf < 4; ++mf)
#pragma unroll
      for (int r = 0; r < 4; ++r) red[w][mf][g][r] = dacc[mf][r];
  __syncthreads();
  if (tid < 64) {
    int mf = tid >> 4, gg = (tid >> 2) & 3, r = tid & 3;
    float s = red[0][mf][gg][r] + red[1][mf][gg][r] +
              red[2][mf][gg][r] + red[3][mf][gg][r];
    rdinv[tid] = 1.f / s;  // tid == local c index mf*16+gg*4+r
  }
  __syncthreads();

  float rd[4][4];
#pragma unroll
  for (int mf = 0; mf < 4; ++mf)
#pragma unroll
    for (int r = 0; r < 4; ++r) rd[mf][r] = rdinv[mf * 16 + g * 4 + r];

  float lacc[4][4];
#pragma unroll
  for (int mf = 0; mf < 4; ++mf)
#pragma unroll
    for (int r = 0; r < 4; ++r) lacc[mf][r] = 0.f;

  // ---- pass B ----
  for (int lt = w; lt < NLT; lt += 4) {
    bf16x8 z0 = Zb[(lt * 2 + 0) * 64 + lane];
    bf16x8 z1 = Zb[(lt * 2 + 1) * 64 + lane];
    int  l    = lt * 16 + col;
    bool lval = (l < LOUT);
#pragma unroll
    for (int mf = 0; mf < 4; ++mf) {
      f32x4 s = {0.f, 0.f, 0.f, 0.f}, t = {0.f, 0.f, 0.f, 0.f};
      s = __builtin_amdgcn_mfma_f32_16x16x32_bf16(qf[mf][0], z0, s, 0, 0, 0);
      s = __builtin_amdgcn_mfma_f32_16x16x32_bf16(qf[mf][1], z1, s, 0, 0, 0);
      t = __builtin_amdgcn_mfma_f32_16x16x32_bf16(of[mf][0], z0, t, 0, 0, 0);
      t = __builtin_amdgcn_mfma_f32_16x16x32_bf16(of[mf][1], z1, t, 0, 0, 0);
#pragma unroll
      for (int r = 0; r < 4; ++r) {
        float a = __expf(s[r]) * rd[mf][r];
        int   c = cb + mf * 16 + g * 4 + r;
        if (lval && c < CC)
          alpha[(size_t)(b * CC + c) * LOUT + l] = a;
        lacc[mf][r] += lval ? a * t[r] : 0.f;
      }
    }
  }

  // logits reduction
#pragma unroll
  for (int mf = 0; mf < 4; ++mf)
#pragma unroll
    for (int r = 0; r < 4; ++r) {
      float v = lacc[mf][r];
      v += __shfl_xor(v, 1); v += __shfl_xor(v, 2);
      v += __shfl_xor(v, 4); v += __shfl_xor(v, 8);
      lacc[mf][r] = v;
    }
  if (col == 0)
#pragma unroll
    for (int mf = 0; mf < 4; ++mf)
#pragma unroll
      for (int r = 0; r < 4; ++r) red[w][mf][g][r] = lacc[mf][r];
  __syncthreads();
  if (tid < 64) {
    int mf = tid >> 4, gg = (tid >> 2) & 3, r = tid & 3;
    int c = cb + tid;
    if (c < CC) {
      float v = red[0][mf][gg][r] + red[1][mf][gg][r] +
                red[2][mf][gg][r] + red[3][mf][gg][r];
      logits[b * CC + c] = v + outb[c];
    }
  }
}

// ---------------------------------------------------------------------------
extern "C" void kernel_launch(void* const* d_in, const int* in_sizes, int n_in,
                              void* d_out, int out_size, void* d_ws, size_t ws_size,
                              hipStream_t stream) {
  const int*   text  = (const int*)d_in[0];
  const float* embed = (const float*)d_in[1];
  const float* convw = (const float*)d_in[2];
  const float* convb = (const float*)d_in[3];
  const float* Qw    = (const float*)d_in[4];
  const float* outw  = (const float*)d_in[5];
  const float* outb  = (const float*)d_in[6];

  float* out    = (float*)d_out;
  float* logits = out;
  float* alpha  = out + (size_t)BB * CC;

  // Z16 staging lives in the (huge) alpha region; fully overwritten later.
  short* Z16 = (short*)alpha;

  short* wsS = (short*)d_ws;
  short* Zp  = wsS;                                   // B*NLT*2*64*8 shorts
  short* Qp  = Zp + (size_t)BB * NLT * 2 * 64 * 8;    // NT16*2*64*8
  short* Op  = Qp + (size_t)NT16 * 2 * 64 * 8;

  k1_conv<<<dim3((LPAD + 63) / 64, BB), 256, 0, stream>>>(
      text, embed, convw, convb, Z16);
  k_packW<<<(NT16 * 128) / 256, 256, 0, stream>>>(Qw, Qp);
  k_packW<<<(NT16 * 128) / 256, 256, 0, stream>>>(outw, Op);
  k_packZ<<<(BB * NLT * 128) / 256, 256, 0, stream>>>(Z16, Zp);
  k_attn<<<dim3(NCT, BB), 256, 0, stream>>>(Zp, Qp, Op, outb, alpha, logits);
}